// Round 1
// baseline (7291.067 us; speedup 1.0000x reference)
//
#include <hip/hip_runtime.h>

#define B 256
#define T 128
#define D 76
#define H 128
#define G 512   // 4H
#define H2 256  // 2H

__device__ __forceinline__ float sigm(float x){ return 1.0f/(1.0f+__expf(-x)); }
__device__ __forceinline__ float fast_tanh(float x){ return 1.0f - 2.0f/(1.0f + __expf(2.0f*x)); }

__global__ void zero_k(float* p, int n){
  for(int i=blockIdx.x*blockDim.x+threadIdx.x;i<n;i+=gridDim.x*blockDim.x) p[i]=0.f;
}

// in [Gn][R][C] -> out [Gn][C][R]
__global__ void transpose_k(const float* __restrict__ in, float* __restrict__ out, int Gn, int R, int C){
  int total=Gn*R*C;
  for(int i=blockIdx.x*blockDim.x+threadIdx.x;i<total;i+=gridDim.x*blockDim.x){
    int g=i/(R*C); int rc=i-g*(R*C); int r=rc/C; int c=rc-r*C;
    out[((size_t)g*C+c)*R + r]=in[i];
  }
}

// One encoder time step, both directions. grid = 256 blocks (d*128 + bpair), 256 thr.
__global__ __launch_bounds__(256) void enc_step_k(
    const float* __restrict__ x, const float* __restrict__ WihT, const float* __restrict__ WhhT,
    const float* __restrict__ bias, float* __restrict__ h_st, float* __restrict__ c_st,
    float* __restrict__ on, int t)
{
  __shared__ float xs[2][D];
  __shared__ float hs[2][H];
  __shared__ float gl[2][G];
  int d = blockIdx.x >> 7;
  int b0 = (blockIdx.x & 127) * 2;
  int tid = threadIdx.x;
  int t_eff = (d==0) ? t : (T-1-t);
  for(int i=tid;i<2*D;i+=256){ int r=i/D,k=i-r*D; xs[r][k]=x[((size_t)(b0+r)*T + t_eff)*D + k]; }
  for(int i=tid;i<2*H;i+=256){ int r=i>>7,k=i&127; hs[r][k]=h_st[(size_t)d*B*H + (size_t)(b0+r)*H + k]; }
  __syncthreads();
  const float* Wi = WihT + (size_t)d*D*G;
  const float* Wh = WhhT + (size_t)d*H*G;
  int j = tid;
  float a00=0,a01=0,a10=0,a11=0;
  for(int k=0;k<D;k++){
    float w0=Wi[k*G+j], w1=Wi[k*G+j+256];
    float x0=xs[0][k], x1=xs[1][k];
    a00+=x0*w0; a01+=x0*w1; a10+=x1*w0; a11+=x1*w1;
  }
  for(int k=0;k<H;k++){
    float w0=Wh[k*G+j], w1=Wh[k*G+j+256];
    float h0v=hs[0][k], h1v=hs[1][k];
    a00+=h0v*w0; a01+=h0v*w1; a10+=h1v*w0; a11+=h1v*w1;
  }
  float bb0=bias[d*G+j], bb1=bias[d*G+j+256];
  gl[0][j]=a00+bb0; gl[0][j+256]=a01+bb1;
  gl[1][j]=a10+bb0; gl[1][j+256]=a11+bb1;
  __syncthreads();
  int r=tid>>7, hh=tid&127, b=b0+r;
  float ii=sigm(gl[r][hh]), ff=sigm(gl[r][128+hh]), gg=fast_tanh(gl[r][256+hh]), oo=sigm(gl[r][384+hh]);
  size_t si=(size_t)d*B*H + (size_t)b*H + hh;
  float cn=ff*c_st[si] + ii*gg;
  float hnv=oo*fast_tanh(cn);
  c_st[si]=cn; h_st[si]=hnv;
  on[((size_t)b*T + t_eff)*H2 + d*H + hh]=hnv;
}

// z = mu_z + eps_z*exp(0.5*logvar_z), written into hbuf[0]. grid=512 (d*256+b), 128 thr.
__global__ __launch_bounds__(128) void z_k(
  const float* __restrict__ h_st, const float* __restrict__ WzmuT, const float* __restrict__ bzmu,
  const float* __restrict__ WzlvT, const float* __restrict__ bzlv, const float* __restrict__ eps_z,
  float* __restrict__ hbuf0)
{
  __shared__ float hr[H];
  int d = blockIdx.x >> 8; int b = blockIdx.x & 255;
  int j = threadIdx.x;
  hr[j] = h_st[(size_t)d*B*H + (size_t)b*H + j];
  __syncthreads();
  float mu=bzmu[j], lv=bzlv[j];
  for(int k=0;k<H;k++){ float hv=hr[k]; mu+=hv*WzmuT[k*H+j]; lv+=hv*WzlvT[k*H+j]; }
  size_t idx=(size_t)d*B*H + (size_t)b*H + j;
  hbuf0[idx] = mu + eps_z[idx]*__expf(0.5f*lv);
}

// on_s = mu_on + eps_on*exp(0.5*logvar_on). 16 rows/block. grid=2048, 256 thr.
__global__ __launch_bounds__(256) void ons_k(
  const float* __restrict__ on, const float* __restrict__ WomuT, const float* __restrict__ bomu,
  const float* __restrict__ WolvT, const float* __restrict__ bolv, const float* __restrict__ eps_on,
  float* __restrict__ on_s)
{
  __shared__ float tile[16][H2];
  size_t row0=(size_t)blockIdx.x*16;
  int tid=threadIdx.x;
  for(int i=tid;i<16*H2;i+=256){ int r=i>>8,c=i&255; tile[r][c]=on[(row0+r)*H2 + c]; }
  __syncthreads();
  int j=tid;
  float am[16], al[16];
  #pragma unroll
  for(int r=0;r<16;r++){am[r]=0.f;al[r]=0.f;}
  for(int k=0;k<H2;k++){
    float wm=WomuT[k*H2+j], wl=WolvT[k*H2+j];
    #pragma unroll
    for(int r=0;r<16;r++){ float v=tile[r][k]; am[r]+=v*wm; al[r]+=v*wl; }
  }
  float bm=bomu[j], bl=bolv[j];
  #pragma unroll
  for(int r=0;r<16;r++){
    size_t row=row0+r;
    on_s[row*H2+j]=am[r]+bm + eps_on[row*H2+j]*__expf(0.5f*(al[r]+bl));
  }
}

// W2v = on_s @ W2T + b2. grid=2048, 256 thr.
__global__ __launch_bounds__(256) void w2v_k(
  const float* __restrict__ on_s, const float* __restrict__ W2T, const float* __restrict__ b2,
  float* __restrict__ W2v)
{
  __shared__ float tile[16][H2];
  size_t row0=(size_t)blockIdx.x*16;
  int tid=threadIdx.x;
  for(int i=tid;i<16*H2;i+=256){ int r=i>>8,c=i&255; tile[r][c]=on_s[(row0+r)*H2 + c]; }
  __syncthreads();
  int j=tid;
  float acc[16];
  #pragma unroll
  for(int r=0;r<16;r++) acc[r]=0.f;
  for(int k=0;k<H2;k++){
    float w=W2T[k*H2+j];
    #pragma unroll
    for(int r=0;r<16;r++) acc[r]+=tile[r][k]*w;
  }
  float bb=b2[j];
  #pragma unroll
  for(int r=0;r<16;r++) W2v[(row0+r)*H2+j]=acc[r]+bb;
}

// One decoder step: blocks [0,256)=attention(b), [256,512)=LSTM cells, [512,576)=outproj of t-1.
__global__ __launch_bounds__(256) void dec_step_k(
  const float* __restrict__ x, const float* __restrict__ WihT, const float* __restrict__ WhhT,
  const float* __restrict__ bias,
  const float* __restrict__ W1T, const float* __restrict__ b1, const float* __restrict__ vv_g,
  const float* __restrict__ W2v, const float* __restrict__ on_s,
  const float* __restrict__ WoutT, const float* __restrict__ bout,
  float* __restrict__ hbuf, float* __restrict__ cbuf, float* __restrict__ ctxb,
  float* __restrict__ out, int t)
{
  int p = t & 1;
  int bid = blockIdx.x;
  int tid = threadIdx.x;
  if (bid < B) {
    // ---- attention for batch row b ----
    __shared__ float q[H2], qp[H2], vv[H2], sc[T], red[256];
    int b = bid;
    const float* hb = hbuf + (size_t)p*2*B*H;
    {
      int dd=tid>>7, k=tid&127;
      q[tid]=hb[(size_t)dd*B*H + (size_t)b*H + k];
      vv[tid]=vv_g[tid];
    }
    __syncthreads();
    float acc=b1[tid];
    for(int k=0;k<H2;k++) acc+=q[k]*W1T[k*H2+tid];
    qp[tid]=acc;
    __syncthreads();
    if (tid<T){
      const float* wrow = W2v + ((size_t)b*T + tid)*H2;
      float s=0.f;
      for(int j=0;j<H2;j++) s += fast_tanh(qp[j]+wrow[j])*vv[j];
      sc[tid]=s;
    }
    __syncthreads();
    red[tid] = (tid<T)? sc[tid] : -1e30f;
    __syncthreads();
    for(int st=128;st>0;st>>=1){ if(tid<st) red[tid]=fmaxf(red[tid],red[tid+st]); __syncthreads(); }
    float m=red[0];
    __syncthreads();
    float ev = (tid<T)? __expf(sc[tid]-m) : 0.f;
    red[tid]=ev;
    if (tid<T) sc[tid]=ev;
    __syncthreads();
    for(int st=128;st>0;st>>=1){ if(tid<st) red[tid]+=red[tid+st]; __syncthreads(); }
    float inv = 1.0f/red[0];
    // ctx
    float c=0.f;
    for(int tt=0;tt<T;tt++) c += sc[tt]*on_s[((size_t)b*T+tt)*H2 + tid];
    ctxb[(size_t)p*B*H2 + (size_t)b*H2 + tid] = c * inv * (1.0f/(float)T);
  } else if (bid < B + 256) {
    // ---- LSTM cells, both dirs ----
    __shared__ float xs[2][D];
    __shared__ float hs[2][H];
    __shared__ float gl[2][G];
    int cb = bid - B;
    int d = cb >> 7;
    int b0 = (cb & 127)*2;
    const float* hb = hbuf + (size_t)p*2*B*H;
    const float* cbp = cbuf + (size_t)p*2*B*H;
    float* hn_ = hbuf + (size_t)(1-p)*2*B*H;
    float* cn_ = cbuf + (size_t)(1-p)*2*B*H;
    if (t>0){
      for(int i=tid;i<2*D;i+=256){ int r=i/D,k=i-r*D; xs[r][k]=x[((size_t)(b0+r)*T + (t-1))*D + k]; }
    }
    for(int i=tid;i<2*H;i+=256){ int r=i>>7,k=i&127; hs[r][k]=hb[(size_t)d*B*H+(size_t)(b0+r)*H+k]; }
    __syncthreads();
    const float* Wi=WihT+(size_t)d*D*G;
    const float* Wh=WhhT+(size_t)d*H*G;
    int j=tid;
    float a00=0,a01=0,a10=0,a11=0;
    if (t>0){
      for(int k=0;k<D;k++){ float w0=Wi[k*G+j],w1=Wi[k*G+j+256],x0=xs[0][k],x1=xs[1][k];
        a00+=x0*w0;a01+=x0*w1;a10+=x1*w0;a11+=x1*w1; }
    }
    for(int k=0;k<H;k++){ float w0=Wh[k*G+j],w1=Wh[k*G+j+256],h0v=hs[0][k],h1v=hs[1][k];
      a00+=h0v*w0;a01+=h0v*w1;a10+=h1v*w0;a11+=h1v*w1; }
    float bb0=bias[d*G+j], bb1=bias[d*G+j+256];
    gl[0][j]=a00+bb0; gl[0][j+256]=a01+bb1;
    gl[1][j]=a10+bb0; gl[1][j+256]=a11+bb1;
    __syncthreads();
    int r=tid>>7, hh=tid&127, b=b0+r;
    float ii=sigm(gl[r][hh]), ff=sigm(gl[r][128+hh]), gg=fast_tanh(gl[r][256+hh]), oo=sigm(gl[r][384+hh]);
    size_t si=(size_t)d*B*H + (size_t)b*H + hh;
    float cn=ff*cbp[si] + ii*gg;
    float hnv=oo*fast_tanh(cn);
    cn_[si]=cn; hn_[si]=hnv;
  } else {
    // ---- output projection for step t-1 ----
    if (t==0) return;
    __shared__ float rowbuf[4][G];
    int ob = bid - B - 256;
    int b0 = ob*4;
    const float* hb = hbuf + (size_t)p*2*B*H;
    const float* cx = ctxb + (size_t)(1-p)*B*H2;
    for(int i=tid;i<4*G;i+=256){
      int r=i>>9, c=i&511;
      float v;
      if (c<H)        v=hb[(size_t)(b0+r)*H + c];
      else if (c<2*H) v=hb[(size_t)B*H + (size_t)(b0+r)*H + (c-H)];
      else            v=cx[(size_t)(b0+r)*H2 + (c-2*H)];
      rowbuf[r][c]=v;
    }
    __syncthreads();
    for(int o=tid;o<4*D;o+=256){
      int r=o/D, j=o-r*D;
      float acc=bout[j];
      for(int k=0;k<G;k++) acc+=rowbuf[r][k]*WoutT[k*D+j];
      out[((size_t)(b0+r)*T + (t-1))*D + j]=acc;
    }
  }
}

// Final output projection for t = T-1: reads hbuf[0] and ctxb[1]. grid=64, 256 thr.
__global__ __launch_bounds__(256) void outproj_final_k(
  const float* __restrict__ hbuf, const float* __restrict__ ctxb,
  const float* __restrict__ WoutT, const float* __restrict__ bout, float* __restrict__ out)
{
  __shared__ float rowbuf[4][G];
  int tid=threadIdx.x;
  int b0 = blockIdx.x*4;
  const float* hb = hbuf;                       // p = T&1 = 0
  const float* cx = ctxb + (size_t)1*B*H2;      // (T-1)&1 = 1
  for(int i=tid;i<4*G;i+=256){
    int r=i>>9, c=i&511;
    float v;
    if (c<H)        v=hb[(size_t)(b0+r)*H + c];
    else if (c<2*H) v=hb[(size_t)B*H + (size_t)(b0+r)*H + (c-H)];
    else            v=cx[(size_t)(b0+r)*H2 + (c-2*H)];
    rowbuf[r][c]=v;
  }
  __syncthreads();
  for(int o=tid;o<4*D;o+=256){
    int r=o/D, j=o-r*D;
    float acc=bout[j];
    for(int k=0;k<G;k++) acc+=rowbuf[r][k]*WoutT[k*D+j];
    out[((size_t)(b0+r)*T + (T-1))*D + j]=acc;
  }
}

extern "C" void kernel_launch(void* const* d_in, const int* in_sizes, int n_in,
                              void* d_out, int out_size, void* d_ws, size_t ws_size,
                              hipStream_t stream) {
  const float* x      =(const float*)d_in[0];
  const float* eps_z  =(const float*)d_in[1];
  const float* eps_on =(const float*)d_in[2];
  const float* enc_Wih=(const float*)d_in[3];
  const float* enc_Whh=(const float*)d_in[4];
  const float* enc_b  =(const float*)d_in[5];
  const float* dec_Wih=(const float*)d_in[6];
  const float* dec_Whh=(const float*)d_in[7];
  const float* dec_b  =(const float*)d_in[8];
  const float* Wzmu=(const float*)d_in[9];  const float* bzmu=(const float*)d_in[10];
  const float* Wzlv=(const float*)d_in[11]; const float* bzlv=(const float*)d_in[12];
  const float* Womu=(const float*)d_in[13]; const float* bomu=(const float*)d_in[14];
  const float* Wolv=(const float*)d_in[15]; const float* bolv=(const float*)d_in[16];
  const float* att_v=(const float*)d_in[17];
  const float* att_W1=(const float*)d_in[18]; const float* att_b1=(const float*)d_in[19];
  const float* att_W2=(const float*)d_in[20]; const float* att_b2=(const float*)d_in[21];
  const float* Wout=(const float*)d_in[22];  const float* bout=(const float*)d_in[23];
  float* out=(float*)d_out;
  float* ws=(float*)d_ws;

  size_t o=0;
  float* encWihT=ws+o; o+=2*D*G;     // [d][k<76][j<512]
  float* encWhhT=ws+o; o+=2*H*G;
  float* decWihT=ws+o; o+=2*D*G;
  float* decWhhT=ws+o; o+=2*H*G;
  float* WzmuT=ws+o; o+=H*H;
  float* WzlvT=ws+o; o+=H*H;
  float* WomuT=ws+o; o+=H2*H2;
  float* WolvT=ws+o; o+=H2*H2;
  float* W1T  =ws+o; o+=H2*H2;
  float* W2T  =ws+o; o+=H2*H2;
  float* WoutT=ws+o; o+=G*D;
  float* h_enc=ws+o; o+=2*B*H;       // h_enc,c_enc contiguous for joint zeroing
  float* c_enc=ws+o; o+=2*B*H;
  float* on   =ws+o; o+=(size_t)B*T*H2;
  float* on_s =ws+o; o+=(size_t)B*T*H2;
  float* W2v  =ws+o; o+=(size_t)B*T*H2;
  float* hbuf =ws+o; o+=2*2*B*H;     // double-buffered [p][d][b][h]
  float* cbuf =ws+o; o+=2*2*B*H;
  float* ctxb =ws+o; o+=2*(size_t)B*H2;
  (void)ws_size; (void)n_in; (void)in_sizes; (void)out_size;

  // weight transposes
  transpose_k<<<256,256,0,stream>>>(enc_Wih, encWihT, 2, G, D);
  transpose_k<<<256,256,0,stream>>>(enc_Whh, encWhhT, 2, G, H);
  transpose_k<<<256,256,0,stream>>>(dec_Wih, decWihT, 2, G, D);
  transpose_k<<<256,256,0,stream>>>(dec_Whh, decWhhT, 2, G, H);
  transpose_k<<<64,256,0,stream>>>(Wzmu, WzmuT, 1, H, H);
  transpose_k<<<64,256,0,stream>>>(Wzlv, WzlvT, 1, H, H);
  transpose_k<<<256,256,0,stream>>>(Womu, WomuT, 1, H2, H2);
  transpose_k<<<256,256,0,stream>>>(Wolv, WolvT, 1, H2, H2);
  transpose_k<<<256,256,0,stream>>>(att_W1, W1T, 1, H2, H2);
  transpose_k<<<256,256,0,stream>>>(att_W2, W2T, 1, H2, H2);
  transpose_k<<<64,256,0,stream>>>(Wout, WoutT, 1, D, G);
  // zero encoder state (h_enc+c_enc contiguous) and decoder c buffer p=0
  zero_k<<<256,256,0,stream>>>(h_enc, 2*2*B*H);
  zero_k<<<256,256,0,stream>>>(cbuf, 2*B*H);

  // encoder
  for(int t=0;t<T;t++)
    enc_step_k<<<256,256,0,stream>>>(x,encWihT,encWhhT,enc_b,h_enc,c_enc,on,t);

  // VAE z -> decoder initial h (hbuf[0])
  z_k<<<512,128,0,stream>>>(h_enc, WzmuT,bzmu,WzlvT,bzlv,eps_z, hbuf);

  // on_s and attention key projection
  ons_k<<<2048,256,0,stream>>>(on,WomuT,bomu,WolvT,bolv,eps_on,on_s);
  w2v_k<<<2048,256,0,stream>>>(on_s,W2T,att_b2,W2v);

  // decoder
  for(int t=0;t<T;t++)
    dec_step_k<<<B+256+64,256,0,stream>>>(x,decWihT,decWhhT,dec_b,W1T,att_b1,att_v,
                                          W2v,on_s,WoutT,bout,hbuf,cbuf,ctxb,out,t);
  outproj_final_k<<<64,256,0,stream>>>(hbuf,ctxb,WoutT,bout,out);
}

// Round 2
// 3676.540 us; speedup vs baseline: 1.9831x; 1.9831x over previous
//
#include <hip/hip_runtime.h>

#define B 256
#define T 128
#define D 76
#define H 128
#define G 512   // 4H
#define H2 256  // 2H

typedef unsigned int uint32;
typedef unsigned short ushort16;

__device__ __forceinline__ float sigm(float x){ return 1.0f/(1.0f+__expf(-x)); }
__device__ __forceinline__ float fast_rcp(float x){ float r; asm volatile("v_rcp_f32 %0, %1" : "=v"(r) : "v"(x)); return r; }
__device__ __forceinline__ float fast_tanh(float x){ return 1.0f - 2.0f*fast_rcp(1.0f + __expf(2.0f*x)); }
__device__ __forceinline__ float bflo(uint32 u){ return __uint_as_float(u<<16); }
__device__ __forceinline__ float bfhi(uint32 u){ return __uint_as_float(u & 0xffff0000u); }
__device__ __forceinline__ float bf2f(ushort16 s){ return __uint_as_float(((uint32)s)<<16); }
__device__ __forceinline__ ushort16 f2bf(float f){
  uint32 u=__float_as_uint(f); uint32 r=(u + 0x7fffu + ((u>>16)&1u))>>16; return (ushort16)r;
}

// ---------- fused weight transposes ----------
struct PrepArgs {
  const float* src[11];
  float* dst[11];
  int Gn[11]; int R[11]; int C[11];
};
__global__ __launch_bounds__(256) void prep_k(PrepArgs a){
  int seg = blockIdx.x >> 5;
  const float* s=a.src[seg]; float* d=a.dst[seg];
  int R=a.R[seg], C=a.C[seg], tot=a.Gn[seg]*R*C;
  for (int i=(blockIdx.x&31)*256+threadIdx.x; i<tot; i+=32*256){
    int g=i/(R*C); int rc=i-g*(R*C); int r=rc/C, c=rc-r*C;
    d[((size_t)g*C+c)*R + r] = s[i];
  }
}

// ---------- encoder: one kernel, block = (dir, 4 batch rows), loops all T ----------
__global__ __launch_bounds__(256) void enc_all_k(
    const float* __restrict__ x, const float* __restrict__ WihT, const float* __restrict__ WhhT,
    const float* __restrict__ bias, float* __restrict__ on, float* __restrict__ h_fin)
{
  int d = blockIdx.x >> 6;
  int b0 = (blockIdx.x & 63) * 4;
  int tid = threadIdx.x;
  __shared__ float hs[4][H], cs4[4][H], xs[4][D], gl[4][G];
  for (int i=tid;i<4*H;i+=256){ hs[i>>7][i&127]=0.f; cs4[i>>7][i&127]=0.f; }
  const float* Wi = WihT + (size_t)d*D*G;
  const float* Wh = WhhT + (size_t)d*H*G;
  float bb0 = bias[d*G+tid], bb1 = bias[d*G+tid+256];
  __syncthreads();
  for (int t=0;t<T;t++){
    int te = d ? (T-1-t) : t;
    for (int i=tid;i<4*D;i+=256){ int r=i/D,k=i-r*D; xs[r][k]=x[((size_t)(b0+r)*T+te)*D+k]; }
    __syncthreads();
    float a0[4]={bb0,bb0,bb0,bb0}, a1[4]={bb1,bb1,bb1,bb1};
    #pragma unroll 4
    for (int k=0;k<D;k++){
      float w0=Wi[k*G+tid], w1=Wi[k*G+tid+256];
      #pragma unroll
      for(int r=0;r<4;r++){ a0[r]+=xs[r][k]*w0; a1[r]+=xs[r][k]*w1; }
    }
    #pragma unroll 4
    for (int k=0;k<H;k++){
      float w0=Wh[k*G+tid], w1=Wh[k*G+tid+256];
      #pragma unroll
      for(int r=0;r<4;r++){ a0[r]+=hs[r][k]*w0; a1[r]+=hs[r][k]*w1; }
    }
    #pragma unroll
    for(int r=0;r<4;r++){ gl[r][tid]=a0[r]; gl[r][tid+256]=a1[r]; }
    __syncthreads();
    #pragma unroll
    for (int u=0;u<2;u++){
      int cell = tid + u*256; int r = cell>>7, hh = cell&127;
      float ii=sigm(gl[r][hh]), ff=sigm(gl[r][128+hh]), gg=fast_tanh(gl[r][256+hh]), oo=sigm(gl[r][384+hh]);
      float cn = ff*cs4[r][hh] + ii*gg;
      float hv = oo*fast_tanh(cn);
      cs4[r][hh]=cn; hs[r][hh]=hv;
      on[((size_t)(b0+r)*T + te)*H2 + d*H + hh] = hv;
    }
    __syncthreads();
  }
  for (int i=tid;i<4*H;i+=256){ int r=i>>7,hh=i&127; h_fin[(size_t)d*B*H+(size_t)(b0+r)*H+hh]=hs[r][hh]; }
}

// ---------- decoder recurrence (cells only), writes h_state[1..T] ----------
__global__ __launch_bounds__(256) void dec_rec_k(
    const float* __restrict__ x, const float* __restrict__ WihT, const float* __restrict__ WhhT,
    const float* __restrict__ bias, float* __restrict__ h_state)
{
  int d = blockIdx.x >> 6;
  int b0 = (blockIdx.x & 63) * 4;
  int tid = threadIdx.x;
  __shared__ float hs[4][H], cs4[4][H], xs[4][D], gl[4][G];
  for (int i=tid;i<4*H;i+=256){
    int r=i>>7,hh=i&127;
    hs[r][hh]=h_state[(size_t)d*B*H + (size_t)(b0+r)*H + hh];
    cs4[r][hh]=0.f;
  }
  const float* Wi = WihT + (size_t)d*D*G;
  const float* Wh = WhhT + (size_t)d*H*G;
  float bb0 = bias[d*G+tid], bb1 = bias[d*G+tid+256];
  __syncthreads();
  for (int t=0;t<T;t++){
    if (t>0){
      for (int i=tid;i<4*D;i+=256){ int r=i/D,k=i-r*D; xs[r][k]=x[((size_t)(b0+r)*T+(t-1))*D+k]; }
    }
    __syncthreads();
    float a0[4]={bb0,bb0,bb0,bb0}, a1[4]={bb1,bb1,bb1,bb1};
    if (t>0){
      #pragma unroll 4
      for (int k=0;k<D;k++){
        float w0=Wi[k*G+tid], w1=Wi[k*G+tid+256];
        #pragma unroll
        for(int r=0;r<4;r++){ a0[r]+=xs[r][k]*w0; a1[r]+=xs[r][k]*w1; }
      }
    }
    #pragma unroll 4
    for (int k=0;k<H;k++){
      float w0=Wh[k*G+tid], w1=Wh[k*G+tid+256];
      #pragma unroll
      for(int r=0;r<4;r++){ a0[r]+=hs[r][k]*w0; a1[r]+=hs[r][k]*w1; }
    }
    #pragma unroll
    for(int r=0;r<4;r++){ gl[r][tid]=a0[r]; gl[r][tid+256]=a1[r]; }
    __syncthreads();
    #pragma unroll
    for (int u=0;u<2;u++){
      int cell = tid + u*256; int r = cell>>7, hh = cell&127;
      float ii=sigm(gl[r][hh]), ff=sigm(gl[r][128+hh]), gg=fast_tanh(gl[r][256+hh]), oo=sigm(gl[r][384+hh]);
      float cn = ff*cs4[r][hh] + ii*gg;
      float hv = oo*fast_tanh(cn);
      cs4[r][hh]=cn; hs[r][hh]=hv;
      h_state[(size_t)(t+1)*2*B*H + (size_t)d*B*H + (size_t)(b0+r)*H + hh] = hv;
    }
    __syncthreads();
  }
}

// ---------- z = mu + eps*exp(0.5 lv) -> h_state[0] ----------
__global__ __launch_bounds__(128) void z_k(
  const float* __restrict__ h_fin, const float* __restrict__ WzmuT, const float* __restrict__ bzmu,
  const float* __restrict__ WzlvT, const float* __restrict__ bzlv, const float* __restrict__ eps_z,
  float* __restrict__ h_state0)
{
  __shared__ float hr[H];
  int d = blockIdx.x >> 8; int b = blockIdx.x & 255;
  int j = threadIdx.x;
  hr[j] = h_fin[(size_t)d*B*H + (size_t)b*H + j];
  __syncthreads();
  float mu=bzmu[j], lv=bzlv[j];
  #pragma unroll 4
  for(int k=0;k<H;k++){ float hv=hr[k]; mu+=hv*WzmuT[k*H+j]; lv+=hv*WzlvT[k*H+j]; }
  size_t idx=(size_t)d*B*H + (size_t)b*H + j;
  h_state0[idx] = mu + eps_z[idx]*__expf(0.5f*lv);
}

// ---------- fused on_s (bf16) + W2v (bf16) ----------
__global__ __launch_bounds__(256) void onsw2v_k(
  const float* __restrict__ on, const float* __restrict__ WomuT, const float* __restrict__ bomu,
  const float* __restrict__ WolvT, const float* __restrict__ bolv, const float* __restrict__ eps_on,
  const float* __restrict__ W2T, const float* __restrict__ b2,
  ushort16* __restrict__ onsb, ushort16* __restrict__ w2vb)
{
  __shared__ float tile[16][H2];
  __shared__ float t2[16][H2];
  size_t row0=(size_t)blockIdx.x*16;
  int tid=threadIdx.x;
  for(int i=tid;i<16*H2;i+=256) tile[i>>8][i&255]=on[row0*H2 + i];
  __syncthreads();
  float am[16], al[16];
  #pragma unroll
  for(int r=0;r<16;r++){am[r]=0.f;al[r]=0.f;}
  for(int k=0;k<H2;k++){
    float wm=WomuT[k*H2+tid], wl=WolvT[k*H2+tid];
    #pragma unroll
    for(int r=0;r<16;r++){ float v=tile[r][k]; am[r]+=v*wm; al[r]+=v*wl; }
  }
  float bm=bomu[tid], bl=bolv[tid];
  #pragma unroll
  for(int r=0;r<16;r++){
    size_t row=row0+r;
    float v = am[r]+bm + eps_on[row*H2+tid]*__expf(0.5f*(al[r]+bl));
    t2[r][tid]=v;
    onsb[row*H2+tid]=f2bf(v);
  }
  __syncthreads();
  float ac[16];
  #pragma unroll
  for(int r=0;r<16;r++) ac[r]=0.f;
  for(int k=0;k<H2;k++){
    float w=W2T[k*H2+tid];
    #pragma unroll
    for(int r=0;r<16;r++) ac[r]+=t2[r][k]*w;
  }
  float bb=b2[tid];
  #pragma unroll
  for(int r=0;r<16;r++) w2vb[(row0+r)*H2+tid]=f2bf(ac[r]+bb);
}

// ---------- qp = concat(h0,h1) @ W1T + b1, all (b,t), bf16 out ----------
__global__ __launch_bounds__(256) void qp_all_k(
  const float* __restrict__ h_state, const float* __restrict__ W1T, const float* __restrict__ b1,
  ushort16* __restrict__ qpb)
{
  int m0 = blockIdx.x*16; int b = m0>>7; int t0 = m0&127;
  __shared__ float tile[16][H2];
  int tid=threadIdx.x;
  for (int i=tid;i<16*H2;i+=256){
    int r=i>>8, k=i&255; int dd=k>>7, kk=k&127;
    tile[r][k] = h_state[(size_t)(t0+r)*2*B*H + (size_t)dd*B*H + (size_t)b*H + kk];
  }
  __syncthreads();
  float ac[16];
  #pragma unroll
  for(int r=0;r<16;r++) ac[r]=0.f;
  for(int k=0;k<H2;k++){
    float w=W1T[k*H2+tid];
    #pragma unroll
    for(int r=0;r<16;r++) ac[r]+=tile[r][k]*w;
  }
  float bb=b1[tid];
  #pragma unroll
  for(int r=0;r<16;r++) qpb[(size_t)(m0+r)*H2+tid]=f2bf(ac[r]+bb);
}

// ---------- attention: block per b, all T queries; W2v/on_s staged bf16 in LDS ----------
#define SWZ(row,c) ((c) ^ ((row)&31))
__global__ __launch_bounds__(512) void attn_k(
  const ushort16* __restrict__ qpb, const ushort16* __restrict__ w2vb, const ushort16* __restrict__ onsb,
  const float* __restrict__ att_v, float* __restrict__ ctx)
{
  int b = blockIdx.x; int tid = threadIdx.x;
  __shared__ uint32 w2[128*128];   // [tt][c dwords], swizzled
  __shared__ uint32 vs[128*128];
  __shared__ float qv[H2], vv[H2], sc[T], part[512], wsum[8];
  const uint32* w2g = (const uint32*)w2vb + (size_t)b*T*128;
  const uint32* vsg = (const uint32*)onsb + (size_t)b*T*128;
  for (int i=tid;i<128*128;i+=512){
    int tt=i>>7, c=i&127;
    w2[tt*128 + SWZ(tt,c)] = w2g[i];
    vs[tt*128 + SWZ(tt,c)] = vsg[i];
  }
  if (tid<H2) vv[tid]=att_v[tid];
  __syncthreads();
  for (int t=0;t<T;t++){
    if (tid<H2) qv[tid] = bf2f(qpb[((size_t)b*T+t)*H2+tid]);
    __syncthreads();
    int tt = tid & 127, q4 = tid >> 7;   // quarter of the j range
    float s=0.f;
    #pragma unroll 4
    for (int c=q4*32; c<q4*32+32; c++){
      uint32 u = w2[tt*128 + SWZ(tt,c)];
      int j=2*c;
      s += fast_tanh(qv[j]+bflo(u))*vv[j] + fast_tanh(qv[j+1]+bfhi(u))*vv[j+1];
    }
    part[tid]=s;
    __syncthreads();
    float ev = 0.f;
    if (tid<T){
      float sv = part[tid]+part[tid+128]+part[tid+256]+part[tid+384];
      ev = __expf(sv);
      sc[tid]=ev;
    }
    #pragma unroll
    for (int off=32; off; off>>=1) ev += __shfl_xor(ev, off);
    if ((tid&63)==0) wsum[tid>>6] = ev;
    __syncthreads();
    float total = wsum[0]+wsum[1];
    float inv = fast_rcp(total*(float)T);
    int j = tid & 255, hf = tid >> 8;
    float acc=0.f;
    int c = j>>1, odd = j&1;
    #pragma unroll 4
    for (int t2=hf*64; t2<hf*64+64; t2++){
      uint32 u = vs[t2*128 + SWZ(t2,c)];
      acc += sc[t2]*(odd? bfhi(u): bflo(u));
    }
    part[tid]=acc;
    __syncthreads();
    if (tid<H2) ctx[((size_t)b*T+t)*H2+tid] = (part[tid]+part[tid+256])*inv;
    __syncthreads();
  }
}

// ---------- output projection, all (b,t) ----------
__global__ __launch_bounds__(256) void outproj_k(
  const float* __restrict__ h_state, const float* __restrict__ ctx,
  const float* __restrict__ WoutT, const float* __restrict__ bout, float* __restrict__ out)
{
  int m0 = blockIdx.x*16; int b = m0>>7; int t0 = m0&127;
  __shared__ float rb[16][G];
  int tid=threadIdx.x;
  for (int i=tid;i<16*G;i+=256){
    int r=i>>9, c=i&511;
    int t = t0+r;
    float v;
    if (c<H)       v = h_state[(size_t)(t+1)*2*B*H + (size_t)b*H + c];
    else if (c<H2) v = h_state[(size_t)(t+1)*2*B*H + (size_t)B*H + (size_t)b*H + (c-H)];
    else           v = ctx[((size_t)(m0+r))*H2 + (c-H2)];
    rb[r][c]=v;
  }
  __syncthreads();
  for (int o=tid;o<16*D;o+=256){
    int r=o/D, j=o-r*D;
    float acc=bout[j];
    #pragma unroll 4
    for (int k=0;k<G;k++) acc += rb[r][k]*WoutT[k*D+j];
    out[((size_t)(m0+r))*D + j]=acc;
  }
}

extern "C" void kernel_launch(void* const* d_in, const int* in_sizes, int n_in,
                              void* d_out, int out_size, void* d_ws, size_t ws_size,
                              hipStream_t stream) {
  const float* x      =(const float*)d_in[0];
  const float* eps_z  =(const float*)d_in[1];
  const float* eps_on =(const float*)d_in[2];
  const float* enc_Wih=(const float*)d_in[3];
  const float* enc_Whh=(const float*)d_in[4];
  const float* enc_b  =(const float*)d_in[5];
  const float* dec_Wih=(const float*)d_in[6];
  const float* dec_Whh=(const float*)d_in[7];
  const float* dec_b  =(const float*)d_in[8];
  const float* Wzmu=(const float*)d_in[9];  const float* bzmu=(const float*)d_in[10];
  const float* Wzlv=(const float*)d_in[11]; const float* bzlv=(const float*)d_in[12];
  const float* Womu=(const float*)d_in[13]; const float* bomu=(const float*)d_in[14];
  const float* Wolv=(const float*)d_in[15]; const float* bolv=(const float*)d_in[16];
  const float* att_v=(const float*)d_in[17];
  const float* att_W1=(const float*)d_in[18]; const float* att_b1=(const float*)d_in[19];
  const float* att_W2=(const float*)d_in[20]; const float* att_b2=(const float*)d_in[21];
  const float* Wout=(const float*)d_in[22];  const float* bout=(const float*)d_in[23];
  float* out=(float*)d_out;
  float* ws=(float*)d_ws;
  (void)ws_size; (void)n_in; (void)in_sizes; (void)out_size;

  size_t o=0;
  float* encWihT=ws+o; o+=2*D*G;
  float* encWhhT=ws+o; o+=2*H*G;
  float* decWihT=ws+o; o+=2*D*G;
  float* decWhhT=ws+o; o+=2*H*G;
  float* WzmuT=ws+o; o+=H*H;
  float* WzlvT=ws+o; o+=H*H;
  float* WomuT=ws+o; o+=H2*H2;
  float* WolvT=ws+o; o+=H2*H2;
  float* W1T  =ws+o; o+=H2*H2;
  float* W2T  =ws+o; o+=H2*H2;
  float* WoutT=ws+o; o+=G*D;
  float* h_fin=ws+o; o+=2*B*H;
  float* on   =ws+o; o+=(size_t)B*T*H2;
  float* h_state=ws+o; o+=(size_t)(T+1)*2*B*H;
  float* ctx  =ws+o; o+=(size_t)B*T*H2;
  ushort16* qpb =(ushort16*)(ws+o); o+=(size_t)B*T*H2/2;
  ushort16* onsb=(ushort16*)(ws+o); o+=(size_t)B*T*H2/2;
  ushort16* w2vb=(ushort16*)(ws+o); o+=(size_t)B*T*H2/2;

  PrepArgs pa;
  const float* srcs[11]={enc_Wih,enc_Whh,dec_Wih,dec_Whh,Wzmu,Wzlv,Womu,Wolv,att_W1,att_W2,Wout};
  float* dsts[11]={encWihT,encWhhT,decWihT,decWhhT,WzmuT,WzlvT,WomuT,WolvT,W1T,W2T,WoutT};
  int Gns[11]={2,2,2,2,1,1,1,1,1,1,1};
  int Rs[11]={G,G,G,G,H,H,H2,H2,H2,H2,D};
  int Cs[11]={D,H,D,H,H,H,H2,H2,H2,H2,G};
  for(int i=0;i<11;i++){pa.src[i]=srcs[i];pa.dst[i]=dsts[i];pa.Gn[i]=Gns[i];pa.R[i]=Rs[i];pa.C[i]=Cs[i];}
  prep_k<<<352,256,0,stream>>>(pa);

  enc_all_k<<<128,256,0,stream>>>(x,encWihT,encWhhT,enc_b,on,h_fin);
  z_k<<<512,128,0,stream>>>(h_fin,WzmuT,bzmu,WzlvT,bzlv,eps_z,h_state);
  onsw2v_k<<<2048,256,0,stream>>>(on,WomuT,bomu,WolvT,bolv,eps_on,W2T,att_b2,onsb,w2vb);
  dec_rec_k<<<128,256,0,stream>>>(x,decWihT,decWhhT,dec_b,h_state);
  qp_all_k<<<2048,256,0,stream>>>(h_state,W1T,att_b1,qpb);
  attn_k<<<B,512,0,stream>>>(qpb,w2vb,onsb,att_v,ctx);
  outproj_k<<<2048,256,0,stream>>>(h_state,ctx,WoutT,bout,out);
}

// Round 3
// 2308.675 us; speedup vs baseline: 3.1581x; 1.5925x over previous
//
#include <hip/hip_runtime.h>
#include <hip/hip_fp16.h>

#define B 256
#define T 128
#define D 76
#define H 128
#define G 512   // 4H
#define H2 256  // 2H

typedef unsigned int uint32;
typedef unsigned short ushort16;

__device__ __forceinline__ float sigm(float x){ return 1.0f/(1.0f+__expf(-x)); }
__device__ __forceinline__ float fast_rcp(float x){ float r; asm volatile("v_rcp_f32 %0, %1" : "=v"(r) : "v"(x)); return r; }
__device__ __forceinline__ float fast_tanh(float x){ return 1.0f - 2.0f*fast_rcp(1.0f + __expf(2.0f*x)); }
__device__ __forceinline__ float bflo(uint32 u){ return __uint_as_float(u<<16); }
__device__ __forceinline__ float bfhi(uint32 u){ return __uint_as_float(u & 0xffff0000u); }
__device__ __forceinline__ float bf2f(ushort16 s){ return __uint_as_float(((uint32)s)<<16); }
__device__ __forceinline__ ushort16 f2bf(float f){ uint32 u=__float_as_uint(f); return (ushort16)((u + 0x7fffu + ((u>>16)&1u))>>16); }
__device__ __forceinline__ float h2f_lo(uint32 u){ return __half2float(__ushort_as_half((unsigned short)(u & 0xffffu))); }
__device__ __forceinline__ float h2f_hi(uint32 u){ return __half2float(__ushort_as_half((unsigned short)(u >> 16))); }
__device__ __forceinline__ uint32 pk_f16(float a, float b){
  return (uint32)__half_as_ushort(__float2half(a)) | ((uint32)__half_as_ushort(__float2half(b))<<16);
}

// ---------- fused weight transposes (9 segs) ----------
struct PrepArgs {
  const float* src[9];
  float* dst[9];
  int Gn[9]; int R[9]; int C[9];
};
__global__ __launch_bounds__(256) void prep_k(PrepArgs a){
  int seg = blockIdx.x >> 5;
  const float* s=a.src[seg]; float* d=a.dst[seg];
  int R=a.R[seg], C=a.C[seg], tot=a.Gn[seg]*R*C;
  for (int i=(blockIdx.x&31)*256+threadIdx.x; i<tot; i+=32*256){
    int g=i/(R*C); int rc=i-g*(R*C); int r=rc/C, c=rc-r*C;
    d[((size_t)g*C+c)*R + r] = s[i];
  }
}

// ---------- pack Whh (enc+dec) into f16 k-paired uint2: [phase][d][k2][j] ----------
// val.x = (W[j][2k2], W[j][2k2+1]) f16x2 ; val.y = same for gate j+256
__global__ __launch_bounds__(256) void pack_whh_k(
  const float* __restrict__ eWhh, const float* __restrict__ dWhh,
  uint2* __restrict__ whhpE, uint2* __restrict__ whhpD)
{
  int idx = blockIdx.x*256 + threadIdx.x;      // 65536 total
  int phase = idx >> 15;
  int rem = idx & 32767;
  int d = rem >> 14;
  int k2 = (rem >> 8) & 63;
  int j = rem & 255;
  const float* Wsrc = phase ? dWhh : eWhh;
  size_t base = ((size_t)(d*512 + j))*128 + 2*k2;
  float2 wa = *(const float2*)(Wsrc + base);
  float2 wb = *(const float2*)(Wsrc + base + (size_t)256*128);
  uint2 v; v.x = pk_f16(wa.x, wa.y); v.y = pk_f16(wb.x, wb.y);
  (phase ? whhpD : whhpE)[rem] = v;
}

// ---------- xg = x @ Wih^T + b, f16-packed pairs (j, j+256). shift=1 for decoder (x[t-1], zeros at t=0) ----------
__global__ __launch_bounds__(256) void xg_k(
  const float* __restrict__ x, const float* __restrict__ WihT, const float* __restrict__ bias,
  uint32* __restrict__ xgp, int shift)
{
  int d = blockIdx.x >> 11;
  int blk = blockIdx.x & 2047;
  int b = blk >> 3, t0 = (blk & 7) * 16;
  int tid = threadIdx.x;
  __shared__ float xs[16][D];
  for (int i=tid;i<16*D;i+=256){
    int r=i/D, k=i-r*D, ts=t0+r-shift;
    xs[r][k] = (ts>=0) ? x[((size_t)b*T+ts)*D + k] : 0.f;
  }
  __syncthreads();
  const float* Wi = WihT + (size_t)d*D*G;
  float a0[16], a1[16];
  #pragma unroll
  for(int r=0;r<16;r++){a0[r]=0.f;a1[r]=0.f;}
  for (int k=0;k<D;k++){
    float w0=Wi[(size_t)k*G+tid], w1=Wi[(size_t)k*G+tid+256];
    #pragma unroll
    for(int r=0;r<16;r++){ float v=xs[r][k]; a0[r]+=v*w0; a1[r]+=v*w1; }
  }
  float bb0=bias[d*G+tid], bb1=bias[d*G+tid+256];
  #pragma unroll
  for(int r=0;r<16;r++)
    xgp[((size_t)(d*B + b)*T + (t0+r))*256 + tid] = pk_f16(a0[r]+bb0, a1[r]+bb1);
}

// ---------- recurrence: block=(dir, 2 rows), Whh f16 in LDS, loops all T ----------
// ENC=1: reads xg at te (reversed for d=1), writes on16 + h_fin. ENC=0: reads h0, writes h_state[t+1].
template<int ENC>
__global__ __launch_bounds__(256,1) void rec_k(
  const uint32* __restrict__ xgp, const uint2* __restrict__ whhp,
  const float* __restrict__ h0, __half* __restrict__ on16,
  float* __restrict__ h_fin, float* __restrict__ h_state)
{
  int d = blockIdx.x >> 7;
  int b0 = (blockIdx.x & 127) * 2;
  int tid = threadIdx.x;
  __shared__ uint2 wlds[64*256];       // 128 KB
  __shared__ float hs[2][H];
  __shared__ float gl[2][G];
  const uint2* wp = whhp + (size_t)d*16384;
  for (int i=tid;i<16384;i+=256) wlds[i] = wp[i];
  int r_c = tid>>7, hh_c = tid&127;
  if (ENC) hs[r_c][hh_c] = 0.f;
  else     hs[r_c][hh_c] = h0[(size_t)d*B*H + (size_t)(b0+r_c)*H + hh_c];
  float creg = 0.f, hlast = 0.f;
  __syncthreads();
  for (int t=0;t<T;t++){
    int te = ENC ? (d ? (T-1-t) : t) : t;
    uint32 xw0 = xgp[((size_t)(d*B + b0+0)*T + te)*256 + tid];
    uint32 xw1 = xgp[((size_t)(d*B + b0+1)*T + te)*256 + tid];
    float a00=0.f,a01=0.f,a10=0.f,a11=0.f;
    #pragma unroll 8
    for (int k2=0;k2<64;k2++){
      uint2 w = wlds[k2*256 + tid];
      float2 h0v = *(const float2*)&hs[0][2*k2];
      float2 h1v = *(const float2*)&hs[1][2*k2];
      float wl0=h2f_lo(w.x), wh0=h2f_hi(w.x);
      float wl1=h2f_lo(w.y), wh1=h2f_hi(w.y);
      a00 = fmaf(h0v.x, wl0, a00); a00 = fmaf(h0v.y, wh0, a00);
      a01 = fmaf(h0v.x, wl1, a01); a01 = fmaf(h0v.y, wh1, a01);
      a10 = fmaf(h1v.x, wl0, a10); a10 = fmaf(h1v.y, wh0, a10);
      a11 = fmaf(h1v.x, wl1, a11); a11 = fmaf(h1v.y, wh1, a11);
    }
    a00 += h2f_lo(xw0); a01 += h2f_hi(xw0);
    a10 += h2f_lo(xw1); a11 += h2f_hi(xw1);
    gl[0][tid]=a00; gl[0][tid+256]=a01;
    gl[1][tid]=a10; gl[1][tid+256]=a11;
    __syncthreads();
    float ii=sigm(gl[r_c][hh_c]), ff=sigm(gl[r_c][128+hh_c]);
    float gg=fast_tanh(gl[r_c][256+hh_c]), oo=sigm(gl[r_c][384+hh_c]);
    creg = ff*creg + ii*gg;
    float hv = oo*fast_tanh(creg);
    hs[r_c][hh_c] = hv; hlast = hv;
    if (ENC) on16[((size_t)(b0+r_c)*T + te)*H2 + d*H + hh_c] = __float2half(hv);
    else     h_state[(size_t)(t+1)*2*B*H + (size_t)d*B*H + (size_t)(b0+r_c)*H + hh_c] = hv;
    __syncthreads();
  }
  if (ENC) h_fin[(size_t)d*B*H + (size_t)(b0+r_c)*H + hh_c] = hlast;
}

// ---------- z = mu + eps*exp(0.5 lv) -> h_state[0] ----------
__global__ __launch_bounds__(128) void z_k(
  const float* __restrict__ h_fin, const float* __restrict__ WzmuT, const float* __restrict__ bzmu,
  const float* __restrict__ WzlvT, const float* __restrict__ bzlv, const float* __restrict__ eps_z,
  float* __restrict__ h_state0)
{
  __shared__ float hr[H];
  int d = blockIdx.x >> 8; int b = blockIdx.x & 255;
  int j = threadIdx.x;
  hr[j] = h_fin[(size_t)d*B*H + (size_t)b*H + j];
  __syncthreads();
  float mu=bzmu[j], lv=bzlv[j];
  #pragma unroll 4
  for(int k=0;k<H;k++){ float hv=hr[k]; mu+=hv*WzmuT[k*H+j]; lv+=hv*WzlvT[k*H+j]; }
  size_t idx=(size_t)d*B*H + (size_t)b*H + j;
  h_state0[idx] = mu + eps_z[idx]*__expf(0.5f*lv);
}

// ---------- fused on_s (bf16) + W2v (bf16); on read as f16 ----------
__global__ __launch_bounds__(256) void onsw2v_k(
  const uint32* __restrict__ on32, const float* __restrict__ WomuT, const float* __restrict__ bomu,
  const float* __restrict__ WolvT, const float* __restrict__ bolv, const float* __restrict__ eps_on,
  const float* __restrict__ W2T, const float* __restrict__ b2,
  ushort16* __restrict__ onsb, ushort16* __restrict__ w2vb)
{
  __shared__ float tile[16][H2];
  __shared__ float t2[16][H2];
  size_t row0=(size_t)blockIdx.x*16;
  int tid=threadIdx.x;
  for(int i=tid;i<16*128;i+=256){
    uint32 u = on32[row0*128 + i];
    int r=i>>7, c2=i&127;
    tile[r][2*c2]=h2f_lo(u); tile[r][2*c2+1]=h2f_hi(u);
  }
  __syncthreads();
  float am[16], al[16];
  #pragma unroll
  for(int r=0;r<16;r++){am[r]=0.f;al[r]=0.f;}
  for(int k=0;k<H2;k++){
    float wm=WomuT[k*H2+tid], wl=WolvT[k*H2+tid];
    #pragma unroll
    for(int r=0;r<16;r++){ float v=tile[r][k]; am[r]+=v*wm; al[r]+=v*wl; }
  }
  float bm=bomu[tid], bl=bolv[tid];
  #pragma unroll
  for(int r=0;r<16;r++){
    size_t row=row0+r;
    float v = am[r]+bm + eps_on[row*H2+tid]*__expf(0.5f*(al[r]+bl));
    t2[r][tid]=v;
    onsb[row*H2+tid]=f2bf(v);
  }
  __syncthreads();
  float ac[16];
  #pragma unroll
  for(int r=0;r<16;r++) ac[r]=0.f;
  for(int k=0;k<H2;k++){
    float w=W2T[k*H2+tid];
    #pragma unroll
    for(int r=0;r<16;r++) ac[r]+=t2[r][k]*w;
  }
  float bb=b2[tid];
  #pragma unroll
  for(int r=0;r<16;r++) w2vb[(row0+r)*H2+tid]=f2bf(ac[r]+bb);
}

// ---------- qp = concat(h0,h1) @ W1T + b1, all (b,t), bf16 out ----------
__global__ __launch_bounds__(256) void qp_all_k(
  const float* __restrict__ h_state, const float* __restrict__ W1T, const float* __restrict__ b1,
  ushort16* __restrict__ qpb)
{
  int m0 = blockIdx.x*16; int b = m0>>7; int t0 = m0&127;
  __shared__ float tile[16][H2];
  int tid=threadIdx.x;
  for (int i=tid;i<16*H2;i+=256){
    int r=i>>8, k=i&255; int dd=k>>7, kk=k&127;
    tile[r][k] = h_state[(size_t)(t0+r)*2*B*H + (size_t)dd*B*H + (size_t)b*H + kk];
  }
  __syncthreads();
  float ac[16];
  #pragma unroll
  for(int r=0;r<16;r++) ac[r]=0.f;
  for(int k=0;k<H2;k++){
    float w=W1T[k*H2+tid];
    #pragma unroll
    for(int r=0;r<16;r++) ac[r]+=tile[r][k]*w;
  }
  float bb=b1[tid];
  #pragma unroll
  for(int r=0;r<16;r++) qpb[(size_t)(m0+r)*H2+tid]=f2bf(ac[r]+bb);
}

// ---------- attention: block per b, all T queries; W2v/on_s staged bf16 in LDS ----------
#define SWZ(row,c) ((c) ^ ((row)&31))
__global__ __launch_bounds__(512) void attn_k(
  const ushort16* __restrict__ qpb, const ushort16* __restrict__ w2vb, const ushort16* __restrict__ onsb,
  const float* __restrict__ att_v, float* __restrict__ ctx)
{
  int b = blockIdx.x; int tid = threadIdx.x;
  __shared__ uint32 w2[128*128];
  __shared__ uint32 vs[128*128];
  __shared__ float qv[H2], vv[H2], sc[T], part[512], wsum[8];
  const uint32* w2g = (const uint32*)w2vb + (size_t)b*T*128;
  const uint32* vsg = (const uint32*)onsb + (size_t)b*T*128;
  for (int i=tid;i<128*128;i+=512){
    int tt=i>>7, c=i&127;
    w2[tt*128 + SWZ(tt,c)] = w2g[i];
    vs[tt*128 + SWZ(tt,c)] = vsg[i];
  }
  if (tid<H2) vv[tid]=att_v[tid];
  __syncthreads();
  for (int t=0;t<T;t++){
    if (tid<H2) qv[tid] = bf2f(qpb[((size_t)b*T+t)*H2+tid]);
    __syncthreads();
    int tt = tid & 127, q4 = tid >> 7;
    float s=0.f;
    #pragma unroll 4
    for (int c=q4*32; c<q4*32+32; c++){
      uint32 u = w2[tt*128 + SWZ(tt,c)];
      int j=2*c;
      s += fast_tanh(qv[j]+bflo(u))*vv[j] + fast_tanh(qv[j+1]+bfhi(u))*vv[j+1];
    }
    part[tid]=s;
    __syncthreads();
    float ev = 0.f;
    if (tid<T){
      float sv = part[tid]+part[tid+128]+part[tid+256]+part[tid+384];
      ev = __expf(sv);
      sc[tid]=ev;
    }
    #pragma unroll
    for (int off=32; off; off>>=1) ev += __shfl_xor(ev, off);
    if ((tid&63)==0) wsum[tid>>6] = ev;
    __syncthreads();
    float total = wsum[0]+wsum[1];
    float inv = fast_rcp(total*(float)T);
    int j = tid & 255, hf = tid >> 8;
    float acc=0.f;
    int c = j>>1, odd = j&1;
    #pragma unroll 4
    for (int t2=hf*64; t2<hf*64+64; t2++){
      uint32 u = vs[t2*128 + SWZ(t2,c)];
      acc += sc[t2]*(odd? bfhi(u): bflo(u));
    }
    part[tid]=acc;
    __syncthreads();
    if (tid<H2) ctx[((size_t)b*T+t)*H2+tid] = (part[tid]+part[tid+256])*inv;
    __syncthreads();
  }
}

// ---------- output projection, all (b,t) ----------
__global__ __launch_bounds__(256) void outproj_k(
  const float* __restrict__ h_state, const float* __restrict__ ctx,
  const float* __restrict__ WoutT, const float* __restrict__ bout, float* __restrict__ out)
{
  int m0 = blockIdx.x*16; int b = m0>>7; int t0 = m0&127;
  __shared__ float rb[16][G];
  int tid=threadIdx.x;
  for (int i=tid;i<16*G;i+=256){
    int r=i>>9, c=i&511;
    int t = t0+r;
    float v;
    if (c<H)       v = h_state[(size_t)(t+1)*2*B*H + (size_t)b*H + c];
    else if (c<H2) v = h_state[(size_t)(t+1)*2*B*H + (size_t)B*H + (size_t)b*H + (c-H)];
    else           v = ctx[((size_t)(m0+r))*H2 + (c-H2)];
    rb[r][c]=v;
  }
  __syncthreads();
  for (int o=tid;o<16*D;o+=256){
    int r=o/D, j=o-r*D;
    float acc=bout[j];
    #pragma unroll 4
    for (int k=0;k<G;k++) acc += rb[r][k]*WoutT[k*D+j];
    out[((size_t)(m0+r))*D + j]=acc;
  }
}

extern "C" void kernel_launch(void* const* d_in, const int* in_sizes, int n_in,
                              void* d_out, int out_size, void* d_ws, size_t ws_size,
                              hipStream_t stream) {
  const float* x      =(const float*)d_in[0];
  const float* eps_z  =(const float*)d_in[1];
  const float* eps_on =(const float*)d_in[2];
  const float* enc_Wih=(const float*)d_in[3];
  const float* enc_Whh=(const float*)d_in[4];
  const float* enc_b  =(const float*)d_in[5];
  const float* dec_Wih=(const float*)d_in[6];
  const float* dec_Whh=(const float*)d_in[7];
  const float* dec_b  =(const float*)d_in[8];
  const float* Wzmu=(const float*)d_in[9];  const float* bzmu=(const float*)d_in[10];
  const float* Wzlv=(const float*)d_in[11]; const float* bzlv=(const float*)d_in[12];
  const float* Womu=(const float*)d_in[13]; const float* bomu=(const float*)d_in[14];
  const float* Wolv=(const float*)d_in[15]; const float* bolv=(const float*)d_in[16];
  const float* att_v=(const float*)d_in[17];
  const float* att_W1=(const float*)d_in[18]; const float* att_b1=(const float*)d_in[19];
  const float* att_W2=(const float*)d_in[20]; const float* att_b2=(const float*)d_in[21];
  const float* Wout=(const float*)d_in[22];  const float* bout=(const float*)d_in[23];
  float* out=(float*)d_out;
  float* ws=(float*)d_ws;
  (void)ws_size; (void)n_in; (void)in_sizes; (void)out_size;

  size_t o=0;
  float* encWihT=ws+o; o+=2*D*G;                 // 77824
  float* decWihT=ws+o; o+=2*D*G;
  float* WzmuT=ws+o; o+=H*H;
  float* WzlvT=ws+o; o+=H*H;
  float* WomuT=ws+o; o+=H2*H2;
  float* WolvT=ws+o; o+=H2*H2;
  float* W1T  =ws+o; o+=H2*H2;
  float* W2T  =ws+o; o+=H2*H2;
  float* WoutT=ws+o; o+=G*D;
  uint2* whhpE=(uint2*)(ws+o); o+=65536;         // 32768 uint2
  uint2* whhpD=(uint2*)(ws+o); o+=65536;
  float* h_fin=ws+o; o+=2*B*H;
  __half* on16=(__half*)(ws+o); o+=(size_t)B*T*H2/2;   // f16 encoder outputs
  float* h_state=ws+o; o+=(size_t)(T+1)*2*B*H;
  float* Abase=ws+o; o+=16777216;                // xgE -> xgD -> {qpb, ctx}
  float* Cbase=ws+o; o+=8388608;                 // onsb + w2vb

  uint32* xgp = (uint32*)Abase;
  ushort16* qpb = (ushort16*)Abase;
  float* ctx = Abase + 4194304;
  ushort16* onsb = (ushort16*)Cbase;
  ushort16* w2vb = (ushort16*)(Cbase + 4194304);

  PrepArgs pa;
  const float* srcs[9]={enc_Wih,dec_Wih,Wzmu,Wzlv,Womu,Wolv,att_W1,att_W2,Wout};
  float* dsts[9]={encWihT,decWihT,WzmuT,WzlvT,WomuT,WolvT,W1T,W2T,WoutT};
  int Gns[9]={2,2,1,1,1,1,1,1,1};
  int Rs[9]={G,G,H,H,H2,H2,H2,H2,D};
  int Cs[9]={D,D,H,H,H2,H2,H2,H2,G};
  for(int i=0;i<9;i++){pa.src[i]=srcs[i];pa.dst[i]=dsts[i];pa.Gn[i]=Gns[i];pa.R[i]=Rs[i];pa.C[i]=Cs[i];}
  prep_k<<<288,256,0,stream>>>(pa);
  pack_whh_k<<<256,256,0,stream>>>(enc_Whh, dec_Whh, whhpE, whhpD);

  // encoder phase
  xg_k<<<4096,256,0,stream>>>(x, encWihT, enc_b, xgp, 0);
  rec_k<1><<<256,256,0,stream>>>(xgp, whhpE, nullptr, on16, h_fin, nullptr);
  z_k<<<512,128,0,stream>>>(h_fin, WzmuT,bzmu,WzlvT,bzlv,eps_z, h_state);
  onsw2v_k<<<2048,256,0,stream>>>((const uint32*)on16,WomuT,bomu,WolvT,bolv,eps_on,W2T,att_b2,onsb,w2vb);

  // decoder phase (xg reuses region A)
  xg_k<<<4096,256,0,stream>>>(x, decWihT, dec_b, xgp, 1);
  rec_k<0><<<256,256,0,stream>>>(xgp, whhpD, h_state, nullptr, nullptr, h_state);

  qp_all_k<<<2048,256,0,stream>>>(h_state, W1T, att_b1, qpb);
  attn_k<<<B,512,0,stream>>>(qpb, w2vb, onsb, att_v, ctx);
  outproj_k<<<2048,256,0,stream>>>(h_state, ctx, WoutT, bout, out);
}